// Round 1
// baseline (1049.490 us; speedup 1.0000x reference)
//
#include <hip/hip_runtime.h>
#include <math.h>

// N=8192, D=256, F=64
#define NN 8192
#define DD 256
#define FF 64
#define NSPLIT 4
#define KV_PER_SPLIT (NN / NSPLIT)  // 2048

typedef __attribute__((ext_vector_type(8))) __bf16 bf16x8;
typedef __attribute__((ext_vector_type(4))) float f32x4;

static __device__ __forceinline__ f32x4 mfma16(bf16x8 a, bf16x8 b, f32x4 c) {
    return __builtin_amdgcn_mfma_f32_16x16x32_bf16(a, b, c, 0, 0, 0);
}

// ---------------------------------------------------------------------------
// Kernel 1: projections. One block per node i.
//   q[i,f] = x[i,:]·Wq[i,f,:] + bq[i,f]   (fp32 accum, bf16 store, row-major)
//   k[i,f] = x[i,:]·Wk[f,:]   + bk[f]     (bf16, row-major)
//   v[i,f] = x[i,:]·Wv[f,:]   + bv[f]     (bf16, TRANSPOSED store vT[f][i])
// Thread t: f = t>>2, quarter c = t&3 covers d in [c*64, c*64+64).
// 512 MB Wq stream is the HBM-bound term.
// ---------------------------------------------------------------------------
__global__ __launch_bounds__(256) void proj_kernel(
    const float* __restrict__ x, const float* __restrict__ Wk,
    const float* __restrict__ bk, const float* __restrict__ Wv,
    const float* __restrict__ bv, const float* __restrict__ Wq,
    const float* __restrict__ bq,
    __bf16* __restrict__ q_bf, __bf16* __restrict__ k_bf,
    __bf16* __restrict__ vT)
{
    const int i = blockIdx.x;
    const int t = threadIdx.x;

    __shared__ float4 xs[4 * 17];  // padded stride 17 -> conflict-free b128 reads
    if (t < 64) {
        float4 xv = reinterpret_cast<const float4*>(x + (size_t)i * DD)[t];
        xs[(t >> 4) * 17 + (t & 15)] = xv;
    }
    __syncthreads();

    const int f = t >> 2;
    const int c = t & 3;
    const float4* wq4 = reinterpret_cast<const float4*>(Wq + (size_t)i * FF * DD);
    const float4* wk4 = reinterpret_cast<const float4*>(Wk);
    const float4* wv4 = reinterpret_cast<const float4*>(Wv);

    float aq = 0.f, ak = 0.f, av = 0.f;
#pragma unroll
    for (int j = 0; j < 16; ++j) {
        float4 xx = xs[c * 17 + j];
        float4 a = wq4[t * 16 + j];            // flat float = 64*t + 4*j
        float4 b = wk4[f * 64 + c * 16 + j];
        float4 d = wv4[f * 64 + c * 16 + j];
        aq += a.x * xx.x + a.y * xx.y + a.z * xx.z + a.w * xx.w;
        ak += b.x * xx.x + b.y * xx.y + b.z * xx.z + b.w * xx.w;
        av += d.x * xx.x + d.y * xx.y + d.z * xx.z + d.w * xx.w;
    }
    // reduce across the 4 quarters (adjacent lanes)
    aq += __shfl_xor(aq, 1, 64); aq += __shfl_xor(aq, 2, 64);
    ak += __shfl_xor(ak, 1, 64); ak += __shfl_xor(ak, 2, 64);
    av += __shfl_xor(av, 1, 64); av += __shfl_xor(av, 2, 64);

    if (c == 0) {
        q_bf[(size_t)i * FF + f] = (__bf16)(aq + bq[(size_t)i * FF + f]);
        k_bf[(size_t)i * FF + f] = (__bf16)(ak + bk[f]);
        vT[(size_t)f * NN + i]   = (__bf16)(av + bv[f]);
    }
}

// ---------------------------------------------------------------------------
// Kernel 2: flash attention, transposed-score formulation.
//   S^T[key][qrow] = sum_f K[key][f] * Q[qrow][f]   (MFMA 16x16x32 bf16)
// C-layout: col = lane&15 = qrow  -> softmax stats (m,l) are per-lane.
//   O^T[f][qrow] += sum_key V^T[f][key] * P^T[key][qrow]
// P^T C-layout -> B-frag via in-register shuffles (no LDS).
// Each wave owns 16 q rows; block = 4 waves = 64 q rows; blockIdx.y = KV split.
// Partials (unnormalized O^T, m, l in natural-log domain) go to ws.
// ---------------------------------------------------------------------------
__global__ __launch_bounds__(256) void attn_kernel(
    const __bf16* __restrict__ q_bf, const __bf16* __restrict__ k_bf,
    const __bf16* __restrict__ vT,
    float* __restrict__ Om, float* __restrict__ m_arr, float* __restrict__ l_arr)
{
    const int lane = threadIdx.x & 63;
    const int wave = threadIdx.x >> 6;
    const int g = lane >> 4;      // quad group
    const int qc = lane & 15;     // q column within wave tile
    const int qb = blockIdx.x;
    const int s  = blockIdx.y;
    const int q0 = qb * 64 + wave * 16;
    const int qrow = q0 + qc;
    const float scale = 0.125f;   // 1/sqrt(64)

    // Q as B-operand fragments: B[k=f][n=qrow], lane: n=qc, f = ks*32 + g*8 + j
    const bf16x8 qf0 = *reinterpret_cast<const bf16x8*>(q_bf + (size_t)qrow * FF + g * 8);
    const bf16x8 qf1 = *reinterpret_cast<const bf16x8*>(q_bf + (size_t)qrow * FF + 32 + g * 8);

    f32x4 o[4];
#pragma unroll
    for (int m = 0; m < 4; ++m) o[m] = (f32x4){0.f, 0.f, 0.f, 0.f};
    float mrun = -INFINITY;
    float lrun = 0.f;

    const int kv0 = s * KV_PER_SPLIT;
    const int sl0 = ((g & 1) * 2) * 16 + qc;  // shuffle sources for P^T gather
    const int sl1 = sl0 + 16;
    const bool lowhalf = (g < 2);

    for (int kb = kv0; kb < kv0 + KV_PER_SPLIT; kb += 64) {
        // ---- S^T = K · Q^T  (4 key tiles x 2 k-steps) ----
        f32x4 sc[4];
#pragma unroll
        for (int kt = 0; kt < 4; ++kt) {
            const __bf16* kp = k_bf + (size_t)(kb + kt * 16 + qc) * FF + g * 8;
            bf16x8 a0 = *reinterpret_cast<const bf16x8*>(kp);
            bf16x8 a1 = *reinterpret_cast<const bf16x8*>(kp + 32);
            f32x4 acc = (f32x4){0.f, 0.f, 0.f, 0.f};
            acc = mfma16(a0, qf0, acc);
            acc = mfma16(a1, qf1, acc);
            sc[kt] = acc;
        }

        // ---- online softmax (per-lane stats; keys spread over g,reg) ----
        float mt = sc[0].x;
#pragma unroll
        for (int kt = 0; kt < 4; ++kt) {
            mt = fmaxf(mt, sc[kt].x); mt = fmaxf(mt, sc[kt].y);
            mt = fmaxf(mt, sc[kt].z); mt = fmaxf(mt, sc[kt].w);
        }
        mt = fmaxf(mt, __shfl_xor(mt, 16, 64));
        mt = fmaxf(mt, __shfl_xor(mt, 32, 64));
        const float mnew = fmaxf(mrun, mt * scale);
        const float alpha = __expf(mrun - mnew);

        float p[4][4];
        float psum = 0.f;
#pragma unroll
        for (int kt = 0; kt < 4; ++kt) {
#pragma unroll
            for (int r = 0; r < 4; ++r) {
                float sv = (r == 0) ? sc[kt].x : (r == 1) ? sc[kt].y : (r == 2) ? sc[kt].z : sc[kt].w;
                float pv = __expf(sv * scale - mnew);
                p[kt][r] = pv;
                psum += pv;
            }
        }
        psum += __shfl_xor(psum, 16, 64);
        psum += __shfl_xor(psum, 32, 64);
        lrun = lrun * alpha + psum;
        mrun = mnew;
#pragma unroll
        for (int m = 0; m < 4; ++m) o[m] *= alpha;

        // ---- O^T += V^T · P^T  (2 k-steps over 64 keys) ----
#pragma unroll
        for (int kk = 0; kk < 2; ++kk) {
            // build B-frag: lane needs P^T[key = 32*kk + 8*g + j][qc]
            bf16x8 pb;
#pragma unroll
            for (int r = 0; r < 4; ++r) {
                float A0 = __shfl(p[2 * kk][r], sl0, 64);
                float A1 = __shfl(p[2 * kk][r], sl1, 64);
                float B0 = __shfl(p[2 * kk + 1][r], sl0, 64);
                float B1 = __shfl(p[2 * kk + 1][r], sl1, 64);
                pb[r]     = (__bf16)(lowhalf ? A0 : B0);
                pb[r + 4] = (__bf16)(lowhalf ? A1 : B1);
            }
            const __bf16* vp = vT + (size_t)qc * NN + kb + kk * 32 + g * 8;
#pragma unroll
            for (int m = 0; m < 4; ++m) {
                bf16x8 a = *reinterpret_cast<const bf16x8*>(vp + (size_t)m * 16 * NN);
                o[m] = mfma16(a, pb, o[m]);
            }
        }
    }

    // ---- store partials: Om[s][f][i] (f = m*16 + g*4 + r, i = q0+qc) ----
    float* op = Om + (size_t)s * FF * NN;
#pragma unroll
    for (int m = 0; m < 4; ++m) {
        op[(size_t)(m * 16 + g * 4 + 0) * NN + q0 + qc] = o[m].x;
        op[(size_t)(m * 16 + g * 4 + 1) * NN + q0 + qc] = o[m].y;
        op[(size_t)(m * 16 + g * 4 + 2) * NN + q0 + qc] = o[m].z;
        op[(size_t)(m * 16 + g * 4 + 3) * NN + q0 + qc] = o[m].w;
    }
    if (g == 0) {
        m_arr[s * NN + qrow] = mrun;
        l_arr[s * NN + qrow] = lrun;
    }
}

// ---------------------------------------------------------------------------
// Kernel 3: merge the NSPLIT partials (log-sum-exp) and write fp32 out[i][f].
// Thread mapping: consecutive threads = consecutive i at fixed f so the big
// Om reads are coalesced; the 2 MB scattered out writes are absorbed by L2.
// ---------------------------------------------------------------------------
__global__ __launch_bounds__(256) void combine_kernel(
    const float* __restrict__ Om, const float* __restrict__ m_arr,
    const float* __restrict__ l_arr, float* __restrict__ out)
{
    const int idx = blockIdx.x * 256 + threadIdx.x;  // < FF*NN
    const int f = idx >> 13;        // idx / 8192
    const int i = idx & (NN - 1);

    float m0 = m_arr[0 * NN + i], m1 = m_arr[1 * NN + i];
    float m2 = m_arr[2 * NN + i], m3 = m_arr[3 * NN + i];
    float M = fmaxf(fmaxf(m0, m1), fmaxf(m2, m3));
    float w0 = __expf(m0 - M), w1 = __expf(m1 - M);
    float w2 = __expf(m2 - M), w3 = __expf(m3 - M);
    float L = w0 * l_arr[0 * NN + i] + w1 * l_arr[1 * NN + i] +
              w2 * l_arr[2 * NN + i] + w3 * l_arr[3 * NN + i];
    float acc = w0 * Om[((size_t)0 * FF + f) * NN + i] +
                w1 * Om[((size_t)1 * FF + f) * NN + i] +
                w2 * Om[((size_t)2 * FF + f) * NN + i] +
                w3 * Om[((size_t)3 * FF + f) * NN + i];
    out[(size_t)i * FF + f] = acc / L;
}

// ---------------------------------------------------------------------------
// ws layout (bytes):
//   [0,       1 MiB)  q_bf  bf16 [N][F]
//   [1 MiB,   2 MiB)  k_bf  bf16 [N][F]
//   [2 MiB,   3 MiB)  vT    bf16 [F][N]
//   [3 MiB,  11 MiB)  Om    f32  [NSPLIT][F][N]
//   [11 MiB, +128K)   m_arr f32  [NSPLIT][N]
//   [.. ,    +128K)   l_arr f32  [NSPLIT][N]
// total ~11.8 MiB
// ---------------------------------------------------------------------------
extern "C" void kernel_launch(void* const* d_in, const int* in_sizes, int n_in,
                              void* d_out, int out_size, void* d_ws, size_t ws_size,
                              hipStream_t stream) {
    const float* x  = (const float*)d_in[0];
    const float* Wk = (const float*)d_in[1];
    const float* bk = (const float*)d_in[2];
    const float* Wv = (const float*)d_in[3];
    const float* bv = (const float*)d_in[4];
    const float* Wq = (const float*)d_in[5];
    const float* bq = (const float*)d_in[6];
    float* out = (float*)d_out;

    char* ws = (char*)d_ws;
    __bf16* q_bf = (__bf16*)(ws);
    __bf16* k_bf = (__bf16*)(ws + ((size_t)1 << 20));
    __bf16* vT   = (__bf16*)(ws + ((size_t)2 << 20));
    float*  Om   = (float*)(ws + ((size_t)3 << 20));
    float*  m_a  = (float*)(ws + ((size_t)11 << 20));
    float*  l_a  = (float*)(ws + ((size_t)11 << 20) + (size_t)NSPLIT * NN * 4);

    hipLaunchKernelGGL(proj_kernel, dim3(NN), dim3(256), 0, stream,
                       x, Wk, bk, Wv, bv, Wq, bq, q_bf, k_bf, vT);
    hipLaunchKernelGGL(attn_kernel, dim3(NN / 64, NSPLIT), dim3(256), 0, stream,
                       q_bf, k_bf, vT, Om, m_a, l_a);
    hipLaunchKernelGGL(combine_kernel, dim3(NN * FF / 256), dim3(256), 0, stream,
                       Om, m_a, l_a, out);
}

// Round 2
// 894.680 us; speedup vs baseline: 1.1730x; 1.1730x over previous
//
#include <hip/hip_runtime.h>
#include <math.h>

// N=8192, D=256, F=64
#define NN 8192
#define DD 256
#define FF 64

typedef __attribute__((ext_vector_type(8))) __bf16 bf16x8;
typedef __attribute__((ext_vector_type(4))) __bf16 bf16x4;
typedef __attribute__((ext_vector_type(4))) float f32x4;

static __device__ __forceinline__ f32x4 mfma16(bf16x8 a, bf16x8 b, f32x4 c) {
    return __builtin_amdgcn_mfma_f32_16x16x32_bf16(a, b, c, 0, 0, 0);
}

// ---------------------------------------------------------------------------
// Kernel 1: projections. One block (4 waves) per node i.
// Wave w computes f = w*16..w*16+15 for q, k, v.
// Per (i,f): lane l loads W[f, 4l..4l+3] (fully coalesced 1KB/wave-instr),
// dots with register x-fragment, 6-step butterfly reduce. Wq (512 MB) is the
// HBM-bound stream; Wk/Wv (128 KB) are L2-resident.
// ---------------------------------------------------------------------------
__global__ __launch_bounds__(256) void proj_kernel(
    const float* __restrict__ x, const float* __restrict__ Wk,
    const float* __restrict__ bk, const float* __restrict__ Wv,
    const float* __restrict__ bv, const float* __restrict__ Wq,
    const float* __restrict__ bq,
    __bf16* __restrict__ q_bf, __bf16* __restrict__ k_bf,
    __bf16* __restrict__ vT)
{
    const int i = blockIdx.x;
    const int t = threadIdx.x;
    const int l = t & 63;
    const int w = t >> 6;

    // lane l holds x[i, 4l..4l+3]
    const float4 xf = reinterpret_cast<const float4*>(x)[(size_t)i * 64 + l];

    const float4* wq4 = reinterpret_cast<const float4*>(Wq) + (size_t)i * 4096;
    const float4* wk4 = reinterpret_cast<const float4*>(Wk);
    const float4* wv4 = reinterpret_cast<const float4*>(Wv);

    // ---- q: streams Wq[i] (64 KB) from HBM, coalesced ----
#pragma unroll
    for (int ff = 0; ff < 16; ++ff) {
        const int f = w * 16 + ff;
        float4 a = wq4[f * 64 + l];
        float s = a.x * xf.x + a.y * xf.y + a.z * xf.z + a.w * xf.w;
        s += __shfl_xor(s, 32, 64); s += __shfl_xor(s, 16, 64);
        s += __shfl_xor(s, 8, 64);  s += __shfl_xor(s, 4, 64);
        s += __shfl_xor(s, 2, 64);  s += __shfl_xor(s, 1, 64);
        if (l == 0) q_bf[(size_t)i * FF + f] = (__bf16)(s + bq[(size_t)i * FF + f]);
    }
    // ---- k (L2-resident weights) ----
#pragma unroll
    for (int ff = 0; ff < 16; ++ff) {
        const int f = w * 16 + ff;
        float4 a = wk4[f * 64 + l];
        float s = a.x * xf.x + a.y * xf.y + a.z * xf.z + a.w * xf.w;
        s += __shfl_xor(s, 32, 64); s += __shfl_xor(s, 16, 64);
        s += __shfl_xor(s, 8, 64);  s += __shfl_xor(s, 4, 64);
        s += __shfl_xor(s, 2, 64);  s += __shfl_xor(s, 1, 64);
        if (l == 0) k_bf[(size_t)i * FF + f] = (__bf16)(s + bk[f]);
    }
    // ---- v (stored transposed: vT[f][i]) ----
#pragma unroll
    for (int ff = 0; ff < 16; ++ff) {
        const int f = w * 16 + ff;
        float4 a = wv4[f * 64 + l];
        float s = a.x * xf.x + a.y * xf.y + a.z * xf.z + a.w * xf.w;
        s += __shfl_xor(s, 32, 64); s += __shfl_xor(s, 16, 64);
        s += __shfl_xor(s, 8, 64);  s += __shfl_xor(s, 4, 64);
        s += __shfl_xor(s, 2, 64);  s += __shfl_xor(s, 1, 64);
        if (l == 0) vT[(size_t)f * NN + i] = (__bf16)(s + bv[f]);
    }
}

// ---------------------------------------------------------------------------
// Kernel 2: flash attention, transposed-score formulation.
//   S^T[key][qrow] via mfma(A=K-tile, B=Q-frag): C-layout col = qrow -> m,l
//   are per-lane scalars; row reductions are 2 shfl_xor each.
// P^T -> B-frag transform through a wave-private XOR-swizzled LDS tile
// (4x ds_write_b64 + 2x ds_read_b128 per K-step, no barrier, <=2-way banks).
// blockIdx.y = KV split (nsplit partials merged by kernel 3).
// ---------------------------------------------------------------------------
__global__ __launch_bounds__(256) void attn_kernel(
    const __bf16* __restrict__ q_bf, const __bf16* __restrict__ k_bf,
    const __bf16* __restrict__ vT,
    float* __restrict__ Om, float* __restrict__ m_arr, float* __restrict__ l_arr,
    int kv_per_split)
{
    __shared__ __bf16 pT[4][16][64];  // per-wave P^T tile, XOR-swizzled cols

    const int lane = threadIdx.x & 63;
    const int wave = threadIdx.x >> 6;
    const int g = lane >> 4;      // quad group
    const int qc = lane & 15;     // q column within wave tile
    const int qb = blockIdx.x;
    const int s  = blockIdx.y;
    const int q0 = qb * 64 + wave * 16;
    const int qrow = q0 + qc;
    const float scale = 0.125f;   // 1/sqrt(64)
    const int sw = qc & 7;        // XOR swizzle key

    // Q as B-operand fragments: lane(g,qc): B[k=f][n=qrow], f = ks*32+g*8+j
    const bf16x8 qf0 = *reinterpret_cast<const bf16x8*>(q_bf + (size_t)qrow * FF + g * 8);
    const bf16x8 qf1 = *reinterpret_cast<const bf16x8*>(q_bf + (size_t)qrow * FF + 32 + g * 8);

    f32x4 o[4];
#pragma unroll
    for (int m = 0; m < 4; ++m) o[m] = (f32x4){0.f, 0.f, 0.f, 0.f};
    float mrun = -INFINITY;
    float lrun = 0.f;

    const int kv0 = s * kv_per_split;

    for (int kb = kv0; kb < kv0 + kv_per_split; kb += 64) {
        // ---- S^T = K · Q^T  (4 key tiles x 2 k-steps) ----
        f32x4 sc[4];
#pragma unroll
        for (int kt = 0; kt < 4; ++kt) {
            const __bf16* kp = k_bf + (size_t)(kb + kt * 16 + qc) * FF + g * 8;
            bf16x8 a0 = *reinterpret_cast<const bf16x8*>(kp);
            bf16x8 a1 = *reinterpret_cast<const bf16x8*>(kp + 32);
            f32x4 acc = (f32x4){0.f, 0.f, 0.f, 0.f};
            acc = mfma16(a0, qf0, acc);
            acc = mfma16(a1, qf1, acc);
            sc[kt] = acc;
        }

        // ---- online softmax (per-lane stats; keys spread over g,reg) ----
        float mt = sc[0].x;
#pragma unroll
        for (int kt = 0; kt < 4; ++kt) {
            mt = fmaxf(mt, sc[kt].x); mt = fmaxf(mt, sc[kt].y);
            mt = fmaxf(mt, sc[kt].z); mt = fmaxf(mt, sc[kt].w);
        }
        mt = fmaxf(mt, __shfl_xor(mt, 16, 64));
        mt = fmaxf(mt, __shfl_xor(mt, 32, 64));
        const float mnew = fmaxf(mrun, mt * scale);
        const float alpha = __expf(mrun - mnew);

        float psum = 0.f;
#pragma unroll
        for (int kt = 0; kt < 4; ++kt) {
            float p0 = __expf(sc[kt].x * scale - mnew);
            float p1 = __expf(sc[kt].y * scale - mnew);
            float p2 = __expf(sc[kt].z * scale - mnew);
            float p3 = __expf(sc[kt].w * scale - mnew);
            psum += (p0 + p1) + (p2 + p3);
            // write P^T[key = kt*16 + g*4 + r][qc] as bf16x4, XOR-swizzled:
            // key-block b = kt*2 + (g>>1), col = ((b ^ sw) << 3) + (g&1)*4
            bf16x4 pv;
            pv[0] = (__bf16)p0; pv[1] = (__bf16)p1;
            pv[2] = (__bf16)p2; pv[3] = (__bf16)p3;
            const int b = kt * 2 + (g >> 1);
            *reinterpret_cast<bf16x4*>(&pT[wave][qc][((b ^ sw) << 3) + (g & 1) * 4]) = pv;
        }
        psum += __shfl_xor(psum, 16, 64);
        psum += __shfl_xor(psum, 32, 64);
        lrun = lrun * alpha + psum;
        mrun = mnew;
#pragma unroll
        for (int m = 0; m < 4; ++m) o[m] *= alpha;

        // ---- O^T += V^T · P^T  (2 k-steps over 64 keys) ----
#pragma unroll
        for (int kk = 0; kk < 2; ++kk) {
            // B-frag: lane(g,qc) needs P^T[key = kk*32 + g*8 + j][qc], j=0..7
            const int br = kk * 4 + g;
            bf16x8 pb = *reinterpret_cast<const bf16x8*>(&pT[wave][qc][(br ^ sw) << 3]);
            const __bf16* vp = vT + (size_t)qc * NN + kb + kk * 32 + g * 8;
#pragma unroll
            for (int m = 0; m < 4; ++m) {
                bf16x8 a = *reinterpret_cast<const bf16x8*>(vp + (size_t)m * 16 * NN);
                o[m] = mfma16(a, pb, o[m]);
            }
        }
    }

    // ---- store partials: Om[s][f][i] (f = m*16 + g*4 + r, i = q0+qc) ----
    float* op = Om + (size_t)s * FF * NN;
#pragma unroll
    for (int m = 0; m < 4; ++m) {
        op[(size_t)(m * 16 + g * 4 + 0) * NN + q0 + qc] = o[m].x;
        op[(size_t)(m * 16 + g * 4 + 1) * NN + q0 + qc] = o[m].y;
        op[(size_t)(m * 16 + g * 4 + 2) * NN + q0 + qc] = o[m].z;
        op[(size_t)(m * 16 + g * 4 + 3) * NN + q0 + qc] = o[m].w;
    }
    if (g == 0) {
        m_arr[s * NN + qrow] = mrun;
        l_arr[s * NN + qrow] = lrun;
    }
}

// ---------------------------------------------------------------------------
// Kernel 3: merge nsplit partials (log-sum-exp) -> fp32 out[i][f].
// Consecutive threads = consecutive i (coalesced Om/m/l reads).
// ---------------------------------------------------------------------------
__global__ __launch_bounds__(256) void combine_kernel(
    const float* __restrict__ Om, const float* __restrict__ m_arr,
    const float* __restrict__ l_arr, float* __restrict__ out, int nsplit)
{
    const int idx = blockIdx.x * 256 + threadIdx.x;  // < FF*NN
    const int f = idx >> 13;        // idx / 8192
    const int i = idx & (NN - 1);

    float M = -INFINITY;
    for (int s = 0; s < nsplit; ++s) M = fmaxf(M, m_arr[s * NN + i]);
    float L = 0.f, acc = 0.f;
    for (int s = 0; s < nsplit; ++s) {
        float wgt = __expf(m_arr[s * NN + i] - M);
        L   += wgt * l_arr[s * NN + i];
        acc += wgt * Om[((size_t)s * FF + f) * NN + i];
    }
    out[(size_t)i * FF + f] = acc / L;
}

// ---------------------------------------------------------------------------
// ws layout (bytes):
//   [0,     1 MiB)  q_bf  bf16 [N][F]
//   [1 MiB, 2 MiB)  k_bf  bf16 [N][F]
//   [2 MiB, 3 MiB)  vT    bf16 [F][N]
//   [3 MiB, ...)    Om    f32  [nsplit][F][N]   (2 MiB per split)
//   then            m_arr f32  [nsplit][N]
//   then            l_arr f32  [nsplit][N]
// nsplit=8 needs ~19.5 MiB; falls back to 4 (~11.8 MiB) if ws is smaller.
// ---------------------------------------------------------------------------
extern "C" void kernel_launch(void* const* d_in, const int* in_sizes, int n_in,
                              void* d_out, int out_size, void* d_ws, size_t ws_size,
                              hipStream_t stream) {
    const float* x  = (const float*)d_in[0];
    const float* Wk = (const float*)d_in[1];
    const float* bk = (const float*)d_in[2];
    const float* Wv = (const float*)d_in[3];
    const float* bv = (const float*)d_in[4];
    const float* Wq = (const float*)d_in[5];
    const float* bq = (const float*)d_in[6];
    float* out = (float*)d_out;

    const int nsplit = (ws_size >= (size_t)20447232) ? 8 : 4;
    const int kv_per_split = NN / nsplit;

    char* ws = (char*)d_ws;
    __bf16* q_bf = (__bf16*)(ws);
    __bf16* k_bf = (__bf16*)(ws + ((size_t)1 << 20));
    __bf16* vT   = (__bf16*)(ws + ((size_t)2 << 20));
    float*  Om   = (float*)(ws + ((size_t)3 << 20));
    float*  m_a  = (float*)(ws + ((size_t)3 << 20) + (size_t)nsplit * FF * NN * 4);
    float*  l_a  = (float*)((char*)m_a + (size_t)nsplit * NN * 4);

    hipLaunchKernelGGL(proj_kernel, dim3(NN), dim3(256), 0, stream,
                       x, Wk, bk, Wv, bv, Wq, bq, q_bf, k_bf, vT);
    hipLaunchKernelGGL(attn_kernel, dim3(NN / 64, nsplit), dim3(256), 0, stream,
                       q_bf, k_bf, vT, Om, m_a, l_a, kv_per_split);
    hipLaunchKernelGGL(combine_kernel, dim3(NN * FF / 256), dim3(256), 0, stream,
                       Om, m_a, l_a, out, nsplit);
}

// Round 3
// 765.967 us; speedup vs baseline: 1.3702x; 1.1680x over previous
//
#include <hip/hip_runtime.h>
#include <math.h>

// N=8192, D=256, F=64
#define NN 8192
#define DD 256
#define FF 64

// q is pre-scaled by softmax scale * log2(e) so attention works in exp2 domain
#define QSC (0.125f * 1.4426950408889634f)

typedef __attribute__((ext_vector_type(8))) __bf16 bf16x8;
typedef __attribute__((ext_vector_type(4))) __bf16 bf16x4;
typedef __attribute__((ext_vector_type(4))) float f32x4;

static __device__ __forceinline__ f32x4 mfma16(bf16x8 a, bf16x8 b, f32x4 c) {
    return __builtin_amdgcn_mfma_f32_16x16x32_bf16(a, b, c, 0, 0, 0);
}

// ---------------------------------------------------------------------------
// Kernel 1a: per-node Q projection (streams the 512 MB Wq — the HBM term).
// One block per node i; wave w covers f = w*16..w*16+15.
// Phase 1: lane l keeps 16 register partials pf[ff] = Wq[i,f,4l..4l+3]·x[i,4l..4l+3]
// Phase 2: wave-private LDS transpose (padded stride 17 -> <=2-way banks),
//          4 lanes/f sum 16 partials each, 2 shfl_xor finish. 34 DS ops/wave
//          instead of 96 ds_bpermute.
// ---------------------------------------------------------------------------
__global__ __launch_bounds__(256) void proj_q_kernel(
    const float* __restrict__ x, const float* __restrict__ Wq,
    const float* __restrict__ bq, __bf16* __restrict__ q_bf)
{
    __shared__ float T[4][64 * 17];

    const int i = blockIdx.x;
    const int l = threadIdx.x & 63;
    const int w = threadIdx.x >> 6;

    const float4 xf = reinterpret_cast<const float4*>(x)[(size_t)i * 64 + l];
    const float4* wq4 = reinterpret_cast<const float4*>(Wq) + (size_t)i * 4096;

    float pf[16];
#pragma unroll
    for (int ff = 0; ff < 16; ++ff) {
        const int f = w * 16 + ff;
        float4 a = wq4[f * 64 + l];
        pf[ff] = a.x * xf.x + a.y * xf.y + a.z * xf.z + a.w * xf.w;
    }
#pragma unroll
    for (int ff = 0; ff < 16; ++ff) T[w][l * 17 + ff] = pf[ff];
    // wave-private tile: no barrier needed
    const int f = l & 15;
    const int c = l >> 4;
    float s = 0.f;
#pragma unroll
    for (int j = 0; j < 16; ++j) s += T[w][(c * 16 + j) * 17 + f];
    s += __shfl_xor(s, 16, 64);
    s += __shfl_xor(s, 32, 64);
    if (l < 16)
        q_bf[(size_t)i * FF + w * 16 + l] =
            (__bf16)((s + bq[(size_t)i * FF + w * 16 + l]) * QSC);
}

// ---------------------------------------------------------------------------
// Kernel 1b: shared K/V projections as a small MFMA GEMM.
//   k = x·Wk^T + bk (row-major bf16), v = x·Wv^T + bv (stored vT[f][i]).
// Block = 4 waves; wave handles a 16-row i-tile, all 64 f for both k and v.
// Weights are read once per wave (L1/L2-hot), x cast to bf16 in-flight.
// ---------------------------------------------------------------------------
__global__ __launch_bounds__(256) void proj_kv_kernel(
    const float* __restrict__ x, const float* __restrict__ Wk,
    const float* __restrict__ bk, const float* __restrict__ Wv,
    const float* __restrict__ bv,
    __bf16* __restrict__ k_bf, __bf16* __restrict__ vT)
{
    const int lane = threadIdx.x & 63;
    const int wave = threadIdx.x >> 6;
    const int g = lane >> 4;
    const int qc = lane & 15;
    const int i0 = blockIdx.x * 64 + wave * 16;  // wave's 16-row i-tile

    f32x4 ack[4], acv[4];
#pragma unroll
    for (int nt = 0; nt < 4; ++nt) {
        ack[nt] = (f32x4){0.f, 0.f, 0.f, 0.f};
        acv[nt] = (f32x4){0.f, 0.f, 0.f, 0.f};
    }

    const float4* x4 = reinterpret_cast<const float4*>(x);
#pragma unroll
    for (int ks = 0; ks < 8; ++ks) {
        // A-frag: x[i0+qc][d = ks*32 + g*8 .. +7] -> bf16
        float4 xa = x4[(size_t)(i0 + qc) * 64 + ks * 8 + g * 2];
        float4 xb = x4[(size_t)(i0 + qc) * 64 + ks * 8 + g * 2 + 1];
        bf16x8 af;
        af[0] = (__bf16)xa.x; af[1] = (__bf16)xa.y; af[2] = (__bf16)xa.z; af[3] = (__bf16)xa.w;
        af[4] = (__bf16)xb.x; af[5] = (__bf16)xb.y; af[6] = (__bf16)xb.z; af[7] = (__bf16)xb.w;
#pragma unroll
        for (int nt = 0; nt < 4; ++nt) {
            const float* wkp = Wk + (size_t)(nt * 16 + qc) * DD + ks * 32 + g * 8;
            const float* wvp = Wv + (size_t)(nt * 16 + qc) * DD + ks * 32 + g * 8;
            float4 wa = reinterpret_cast<const float4*>(wkp)[0];
            float4 wb = reinterpret_cast<const float4*>(wkp)[1];
            bf16x8 bk8;
            bk8[0] = (__bf16)wa.x; bk8[1] = (__bf16)wa.y; bk8[2] = (__bf16)wa.z; bk8[3] = (__bf16)wa.w;
            bk8[4] = (__bf16)wb.x; bk8[5] = (__bf16)wb.y; bk8[6] = (__bf16)wb.z; bk8[7] = (__bf16)wb.w;
            ack[nt] = mfma16(af, bk8, ack[nt]);
            float4 va = reinterpret_cast<const float4*>(wvp)[0];
            float4 vb = reinterpret_cast<const float4*>(wvp)[1];
            bf16x8 bv8;
            bv8[0] = (__bf16)va.x; bv8[1] = (__bf16)va.y; bv8[2] = (__bf16)va.z; bv8[3] = (__bf16)va.w;
            bv8[4] = (__bf16)vb.x; bv8[5] = (__bf16)vb.y; bv8[6] = (__bf16)vb.z; bv8[7] = (__bf16)vb.w;
            acv[nt] = mfma16(af, bv8, acv[nt]);
        }
    }

    // C layout: row(i-within-tile) = g*4+r, col(f-within-tile) = qc
#pragma unroll
    for (int nt = 0; nt < 4; ++nt) {
        const int f = nt * 16 + qc;
        const float bkf = bk[f];
        const float bvf = bv[f];
#pragma unroll
        for (int r = 0; r < 4; ++r) {
            const int i = i0 + g * 4 + r;
            k_bf[(size_t)i * FF + f] = (__bf16)(ack[nt][r] + bkf);
            vT[(size_t)f * NN + i]   = (__bf16)(acv[nt][r] + bvf);
        }
    }
}

// ---------------------------------------------------------------------------
// Kernel 2: flash attention, transposed-score formulation, LDS-staged K/V.
// Block = 4 waves, 64 q rows; per 64-key iter the block cooperatively stages
// K-tile (64x64 bf16) and V^T-tile (64x64) into XOR-swizzled LDS (row fully
// aliases the 32 banks, so even blk distribution == aggregate-minimal for
// both the staging writes and the b128 frag reads). 4x less L2 traffic than
// per-wave direct loads. Softmax in exp2 domain (q pre-scaled at proj).
// ---------------------------------------------------------------------------
__global__ __launch_bounds__(256) void attn_kernel(
    const __bf16* __restrict__ q_bf, const __bf16* __restrict__ k_bf,
    const __bf16* __restrict__ vT,
    float* __restrict__ Om, float* __restrict__ m_arr, float* __restrict__ l_arr,
    int kv_per_split)
{
    __shared__ __align__(16) __bf16 Klds[64 * 64];   // [key-row][f], blk^=(row&7)
    __shared__ __align__(16) __bf16 Vlds[64 * 64];   // [f-row][key], blk^=(row&7)
    __shared__ __align__(16) __bf16 pT[4][16 * 64];  // per-wave P^T, blk^=(qc&7)

    const int t = threadIdx.x;
    const int lane = t & 63;
    const int wave = t >> 6;
    const int g = lane >> 4;
    const int qc = lane & 15;
    const int q0 = blockIdx.x * 64 + wave * 16;
    const int s  = blockIdx.y;
    const int qrow = q0 + qc;
    const int sw = qc & 7;

    // staging map: thread t -> row = t>>2, 16B-unit pair bp = (t&3)*2
    const int srow = t >> 2;
    const int sbp  = (t & 3) * 2;

    const bf16x8 qf0 = *reinterpret_cast<const bf16x8*>(q_bf + (size_t)qrow * FF + g * 8);
    const bf16x8 qf1 = *reinterpret_cast<const bf16x8*>(q_bf + (size_t)qrow * FF + 32 + g * 8);

    f32x4 o[4];
#pragma unroll
    for (int m = 0; m < 4; ++m) o[m] = (f32x4){0.f, 0.f, 0.f, 0.f};
    float mrun = -INFINITY;
    float lrun = 0.f;

    const int kv0 = s * kv_per_split;

    for (int kb = kv0; kb < kv0 + kv_per_split; kb += 64) {
        __syncthreads();  // previous iter's frag reads must finish
        {   // stage K tile: Klds[row][f], swizzled
            const __bf16* src = k_bf + (size_t)(kb + srow) * FF + sbp * 8;
            bf16x8 u0 = *reinterpret_cast<const bf16x8*>(src);
            bf16x8 u1 = *reinterpret_cast<const bf16x8*>(src + 8);
            *reinterpret_cast<bf16x8*>(&Klds[srow * 64 + ((sbp ^ (srow & 7)) * 8)]) = u0;
            *reinterpret_cast<bf16x8*>(&Klds[srow * 64 + (((sbp + 1) ^ (srow & 7)) * 8)]) = u1;
            // stage V^T tile: Vlds[f][key]
            const __bf16* sv = vT + (size_t)srow * NN + kb + sbp * 8;
            bf16x8 w0 = *reinterpret_cast<const bf16x8*>(sv);
            bf16x8 w1 = *reinterpret_cast<const bf16x8*>(sv + 8);
            *reinterpret_cast<bf16x8*>(&Vlds[srow * 64 + ((sbp ^ (srow & 7)) * 8)]) = w0;
            *reinterpret_cast<bf16x8*>(&Vlds[srow * 64 + (((sbp + 1) ^ (srow & 7)) * 8)]) = w1;
        }
        __syncthreads();

        // ---- S^T = K · Q^T (scores arrive pre-scaled in log2 domain) ----
        f32x4 sc[4];
#pragma unroll
        for (int kt = 0; kt < 4; ++kt) {
            const int row = kt * 16 + qc;
            bf16x8 a0 = *reinterpret_cast<const bf16x8*>(&Klds[row * 64 + ((g ^ (qc & 7)) * 8)]);
            bf16x8 a1 = *reinterpret_cast<const bf16x8*>(&Klds[row * 64 + (((4 + g) ^ (qc & 7)) * 8)]);
            f32x4 acc = (f32x4){0.f, 0.f, 0.f, 0.f};
            acc = mfma16(a0, qf0, acc);
            acc = mfma16(a1, qf1, acc);
            sc[kt] = acc;
        }

        // ---- online softmax (per-lane stats) ----
        float mt = sc[0].x;
#pragma unroll
        for (int kt = 0; kt < 4; ++kt) {
            mt = fmaxf(mt, sc[kt].x); mt = fmaxf(mt, sc[kt].y);
            mt = fmaxf(mt, sc[kt].z); mt = fmaxf(mt, sc[kt].w);
        }
        mt = fmaxf(mt, __shfl_xor(mt, 16, 64));
        mt = fmaxf(mt, __shfl_xor(mt, 32, 64));
        const float mnew = fmaxf(mrun, mt);
        const float alpha = __builtin_amdgcn_exp2f(mrun - mnew);

        float psum = 0.f;
#pragma unroll
        for (int kt = 0; kt < 4; ++kt) {
            float p0 = __builtin_amdgcn_exp2f(sc[kt].x - mnew);
            float p1 = __builtin_amdgcn_exp2f(sc[kt].y - mnew);
            float p2 = __builtin_amdgcn_exp2f(sc[kt].z - mnew);
            float p3 = __builtin_amdgcn_exp2f(sc[kt].w - mnew);
            psum += (p0 + p1) + (p2 + p3);
            bf16x4 pv;
            pv[0] = (__bf16)p0; pv[1] = (__bf16)p1;
            pv[2] = (__bf16)p2; pv[3] = (__bf16)p3;
            const int b = kt * 2 + (g >> 1);
            *reinterpret_cast<bf16x4*>(&pT[wave][qc * 64 + ((b ^ sw) << 3) + (g & 1) * 4]) = pv;
        }
        psum += __shfl_xor(psum, 16, 64);
        psum += __shfl_xor(psum, 32, 64);
        lrun = lrun * alpha + psum;
        mrun = mnew;
#pragma unroll
        for (int m = 0; m < 4; ++m) o[m] *= alpha;

        // ---- O^T += V^T · P^T ----
#pragma unroll
        for (int kk = 0; kk < 2; ++kk) {
            const int br = kk * 4 + g;
            bf16x8 pb = *reinterpret_cast<const bf16x8*>(&pT[wave][qc * 64 + ((br ^ sw) << 3)]);
#pragma unroll
            for (int m = 0; m < 4; ++m) {
                const int row = m * 16 + qc;
                bf16x8 a = *reinterpret_cast<const bf16x8*>(
                    &Vlds[row * 64 + (((kk * 4 + g) ^ (qc & 7)) * 8)]);
                o[m] = mfma16(a, pb, o[m]);
            }
        }
    }

    // ---- store partials: Om[s][f][i], f = m*16 + g*4 + r ----
    float* op = Om + (size_t)s * FF * NN;
#pragma unroll
    for (int m = 0; m < 4; ++m) {
        op[(size_t)(m * 16 + g * 4 + 0) * NN + q0 + qc] = o[m].x;
        op[(size_t)(m * 16 + g * 4 + 1) * NN + q0 + qc] = o[m].y;
        op[(size_t)(m * 16 + g * 4 + 2) * NN + q0 + qc] = o[m].z;
        op[(size_t)(m * 16 + g * 4 + 3) * NN + q0 + qc] = o[m].w;
    }
    if (g == 0) {
        m_arr[s * NN + qrow] = mrun;   // log2 domain
        l_arr[s * NN + qrow] = lrun;
    }
}

// ---------------------------------------------------------------------------
// Kernel 3: merge nsplit partials (log2-domain LSE) -> fp32 out[i][f].
// ---------------------------------------------------------------------------
__global__ __launch_bounds__(256) void combine_kernel(
    const float* __restrict__ Om, const float* __restrict__ m_arr,
    const float* __restrict__ l_arr, float* __restrict__ out, int nsplit)
{
    const int idx = blockIdx.x * 256 + threadIdx.x;  // < FF*NN
    const int f = idx >> 13;
    const int i = idx & (NN - 1);

    float M = -INFINITY;
    for (int s = 0; s < nsplit; ++s) M = fmaxf(M, m_arr[s * NN + i]);
    float L = 0.f, acc = 0.f;
    for (int s = 0; s < nsplit; ++s) {
        float wgt = __builtin_amdgcn_exp2f(m_arr[s * NN + i] - M);
        L   += wgt * l_arr[s * NN + i];
        acc += wgt * Om[((size_t)s * FF + f) * NN + i];
    }
    out[(size_t)i * FF + f] = acc / L;
}

// ---------------------------------------------------------------------------
// ws layout: q_bf 1 MiB | k_bf 1 MiB | vT 1 MiB | Om nsplit*2 MiB | m | l
// ---------------------------------------------------------------------------
extern "C" void kernel_launch(void* const* d_in, const int* in_sizes, int n_in,
                              void* d_out, int out_size, void* d_ws, size_t ws_size,
                              hipStream_t stream) {
    const float* x  = (const float*)d_in[0];
    const float* Wk = (const float*)d_in[1];
    const float* bk = (const float*)d_in[2];
    const float* Wv = (const float*)d_in[3];
    const float* bv = (const float*)d_in[4];
    const float* Wq = (const float*)d_in[5];
    const float* bq = (const float*)d_in[6];
    float* out = (float*)d_out;

    const int nsplit = (ws_size >= (size_t)20971520) ? 8 : 4;
    const int kv_per_split = NN / nsplit;

    char* ws = (char*)d_ws;
    __bf16* q_bf = (__bf16*)(ws);
    __bf16* k_bf = (__bf16*)(ws + ((size_t)1 << 20));
    __bf16* vT   = (__bf16*)(ws + ((size_t)2 << 20));
    float*  Om   = (float*)(ws + ((size_t)3 << 20));
    float*  m_a  = (float*)(ws + ((size_t)3 << 20) + (size_t)nsplit * FF * NN * 4);
    float*  l_a  = (float*)((char*)m_a + (size_t)nsplit * NN * 4);

    hipLaunchKernelGGL(proj_q_kernel, dim3(NN), dim3(256), 0, stream,
                       x, Wq, bq, q_bf);
    hipLaunchKernelGGL(proj_kv_kernel, dim3(NN / 64), dim3(256), 0, stream,
                       x, Wk, bk, Wv, bv, k_bf, vT);
    hipLaunchKernelGGL(attn_kernel, dim3(NN / 64, nsplit), dim3(256), 0, stream,
                       q_bf, k_bf, vT, Om, m_a, l_a, kv_per_split);
    hipLaunchKernelGGL(combine_kernel, dim3(NN * FF / 256), dim3(256), 0, stream,
                       Om, m_a, l_a, out, nsplit);
}